// Round 2
// baseline (13224.355 us; speedup 1.0000x reference)
//
#include <hip/hip_runtime.h>
#include <hip/hip_bf16.h>

using bf16 = __hip_bfloat16;
typedef short v8s __attribute__((ext_vector_type(8)));   // 8 bf16 = 4 VGPRs
typedef float v4f __attribute__((ext_vector_type(4)));   // MFMA C/D frag

__device__ __forceinline__ float sigmoidf_(float x) {
    return 1.0f / (1.0f + __expf(-x));
}
__device__ __forceinline__ float tanhf_(float x) {
    return 1.0f - 2.0f / (__expf(2.0f * x) + 1.0f);
}
__device__ __forceinline__ unsigned short bfbits(float f) {
    bf16 h = __float2bfloat16(f);
    return *reinterpret_cast<unsigned short*>(&h);
}

// ---------------- fp32 -> bf16 converter ----------------
__global__ void f2b_kernel(const float* __restrict__ s, bf16* __restrict__ d, int n) {
    int idx = blockIdx.x * blockDim.x + threadIdx.x;
    int stride = gridDim.x * blockDim.x;
    for (int i = idx * 4; i < n; i += stride * 4) {
        float4 v = *reinterpret_cast<const float4*>(s + i);
        ushort4 u;
        u.x = bfbits(v.x); u.y = bfbits(v.y); u.z = bfbits(v.z); u.w = bfbits(v.w);
        *reinterpret_cast<ushort4*>(d + i) = u;
    }
}

// ---------------- init states + barrier counters ----------------
// eh/ec: [L,B,H] fp32. hf/cf: [L*B*H] fp32. hbf: [L][2][B*H] bf16 (slot 0 init).
__global__ void init_state_kernel(const float* __restrict__ eh, const float* __restrict__ ec,
                                  float* __restrict__ hf, float* __restrict__ cf,
                                  bf16* __restrict__ hbf, unsigned* __restrict__ counters) {
    int idx = blockIdx.x * blockDim.x + threadIdx.x;
    if (idx < 4) counters[idx * 64] = 0u;   // 4 phase counters, 256B apart
    if (idx >= 2 * 32 * 512) return;
    int l = idx >> 14;          // / 16384
    int rem = idx & 16383;
    hf[idx] = eh[idx];
    cf[idx] = ec[idx];
    hbf[(l * 2 + 0) * 16384 + rem] = __float2bfloat16(eh[idx]);
}

// ---------------- tail: final states -> d_out ----------------
__global__ void tail_kernel(const float* __restrict__ hf, const float* __restrict__ cf,
                            float* __restrict__ out) {
    int idx = blockIdx.x * blockDim.x + threadIdx.x;
    if (idx >= 2 * 32 * 512) return;
    out[1048576 + idx] = hf[idx];
    out[1048576 + 32768 + idx] = cf[idx];
}

// ---------------- bf16 MFMA GEMM: C[M,N] = A[M,K] @ W[N,K]^T (+bias) ----------------
__global__ __launch_bounds__(256) void gemm_bt(
    const bf16* __restrict__ A, const bf16* __restrict__ W,
    const float* __restrict__ bias,
    float* __restrict__ Cf, bf16* __restrict__ Cb,
    int M, int N, int K) {
    __shared__ __align__(16) bf16 As[64][72];
    __shared__ __align__(16) bf16 Bs[64][72];
    const int tid = threadIdx.x;
    const int wave = tid >> 6, lane = tid & 63;
    const int lr = lane & 15, lq = lane >> 4;
    const int m0 = blockIdx.y * 64, n0 = blockIdx.x * 64;

    v4f acc[4];
#pragma unroll
    for (int n = 0; n < 4; ++n) acc[n] = (v4f){0.f, 0.f, 0.f, 0.f};

    for (int k0 = 0; k0 < K; k0 += 64) {
        __syncthreads();
#pragma unroll
        for (int c = tid; c < 512; c += 256) {
            int row = c >> 3, c8 = (c & 7) * 8;
            *reinterpret_cast<v8s*>(&As[row][c8]) =
                *reinterpret_cast<const v8s*>(A + (size_t)(m0 + row) * K + k0 + c8);
            *reinterpret_cast<v8s*>(&Bs[row][c8]) =
                *reinterpret_cast<const v8s*>(W + (size_t)(n0 + row) * K + k0 + c8);
        }
        __syncthreads();
#pragma unroll
        for (int kk = 0; kk < 2; ++kk) {
            v8s a = *reinterpret_cast<const v8s*>(&As[wave * 16 + lr][kk * 32 + lq * 8]);
#pragma unroll
            for (int n = 0; n < 4; ++n) {
                v8s b = *reinterpret_cast<const v8s*>(&Bs[n * 16 + lr][kk * 32 + lq * 8]);
                acc[n] = __builtin_amdgcn_mfma_f32_16x16x32_bf16(a, b, acc[n], 0, 0, 0);
            }
        }
    }
#pragma unroll
    for (int n = 0; n < 4; ++n) {
        int col = n0 + n * 16 + lr;
        float bv = bias ? bias[col] : 0.0f;
#pragma unroll
        for (int r = 0; r < 4; ++r) {
            int row = m0 + wave * 16 + lq * 4 + r;
            float v = acc[n][r] + bv;
            if (Cf) Cf[(size_t)row * N + col] = v;
            if (Cb) Cb[(size_t)row * N + col] = __float2bfloat16(v);
        }
    }
}

// ---------------- persistent LSTM layer ----------------
// 32 WGs x 256 thr, all co-resident (32 << 256 CUs). WG j owns hidden cols
// [j*16, j*16+16). Wave w = gate w (i,f,g,o). Whh slice preloaded to VGPRs.
// Cross-WG sync per timestep: device-scope monotone atomic barrier.
__global__ __launch_bounds__(256) void lstm_layer_persist(
    int T,
    bf16* __restrict__ h0, bf16* __restrict__ h1,  // ping-pong [32*512] bf16
    float* __restrict__ hf, float* __restrict__ cf, // [32*512] fp32 state
    const bf16* __restrict__ Whh,                   // [2048][512]
    const float* __restrict__ xpf,                  // fp32 xproj [(b*T+t)*G] or null
    const bf16* __restrict__ xpb,                   // bf16 xproj or null
    const float* __restrict__ bih, const float* __restrict__ bhh,
    bf16* __restrict__ seq, long seq_stride_b,      // optional bf16 h seq out
    float* __restrict__ outf, long out_stride_b,    // optional fp32 h seq out
    unsigned* __restrict__ bar)
{
    __shared__ float gs[4][32][16];
    __shared__ float bias_s[4][16];
    const int tid = threadIdx.x;
    const int wave = tid >> 6, lane = tid & 63;
    const int lr = lane & 15, lq = lane >> 4;
    const int hc0 = blockIdx.x * 16;

    if (tid < 64) {
        int g = tid >> 4, col = tid & 15;
        bias_s[g][col] = bih[g * 512 + hc0 + col] + bhh[g * 512 + hc0 + col];
    }

    // Preload this wave's Whh slice (gate `wave`, cols hc0+lr) into registers:
    // 16 v8s = 64 VGPRs. Occupancy is irrelevant at 32 WGs on 256 CUs.
    v8s breg[16];
    {
        const bf16* wrow = Whh + (size_t)(wave * 512 + hc0 + lr) * 512 + lq * 8;
#pragma unroll
        for (int kk = 0; kk < 16; ++kk)
            breg[kk] = *reinterpret_cast<const v8s*>(wrow + kk * 32);
    }
    __syncthreads();

    for (int t = 0; t < T; ++t) {
        const bf16* hin = (t & 1) ? h1 : h0;
        bf16* hout      = (t & 1) ? h0 : h1;
        const bf16* arow = hin + (size_t)lr * 512 + lq * 8;

        v4f acc0 = (v4f){0.f, 0.f, 0.f, 0.f};
        v4f acc1 = (v4f){0.f, 0.f, 0.f, 0.f};
#pragma unroll 4
        for (int kk = 0; kk < 16; ++kk) {
            v8s a0 = *reinterpret_cast<const v8s*>(arow + kk * 32);
            v8s a1 = *reinterpret_cast<const v8s*>(arow + 16 * 512 + kk * 32);
            acc0 = __builtin_amdgcn_mfma_f32_16x16x32_bf16(a0, breg[kk], acc0, 0, 0, 0);
            acc1 = __builtin_amdgcn_mfma_f32_16x16x32_bf16(a1, breg[kk], acc1, 0, 0, 0);
        }
#pragma unroll
        for (int r = 0; r < 4; ++r) {
            gs[wave][lq * 4 + r][lr]      = acc0[r];
            gs[wave][16 + lq * 4 + r][lr] = acc1[r];
        }
        __syncthreads();

#pragma unroll
        for (int i = tid; i < 512; i += 256) {
            int b = i >> 4, col = i & 15;
            int gc = hc0 + col;
            float xi, xf, xg, xo;
            if (xpf) {
                const float* xp = xpf + ((size_t)b * T + t) * 2048;
                xi = xp[gc]; xf = xp[512 + gc]; xg = xp[1024 + gc]; xo = xp[1536 + gc];
            } else {
                const bf16* xp = xpb + ((size_t)b * T + t) * 2048;
                xi = __bfloat162float(xp[gc]);
                xf = __bfloat162float(xp[512 + gc]);
                xg = __bfloat162float(xp[1024 + gc]);
                xo = __bfloat162float(xp[1536 + gc]);
            }
            float gi  = gs[0][b][col] + xi + bias_s[0][col];
            float gfv = gs[1][b][col] + xf + bias_s[1][col];
            float gg  = gs[2][b][col] + xg + bias_s[2][col];
            float go  = gs[3][b][col] + xo + bias_s[3][col];

            size_t sidx = (size_t)b * 512 + gc;
            float c_old = cf[sidx];
            float c_new = sigmoidf_(gfv) * c_old + sigmoidf_(gi) * tanhf_(gg);
            float h = sigmoidf_(go) * tanhf_(c_new);
            cf[sidx] = c_new;
            hout[sidx] = __float2bfloat16(h);
            if (t == T - 1) hf[sidx] = h;
            if (seq)  seq[(size_t)b * seq_stride_b + (size_t)t * 512 + gc] = __float2bfloat16(h);
            if (outf) outf[(size_t)b * out_stride_b + (size_t)t * 512 + gc] = h;
        }

        // ---- device-scope grid barrier (monotone counter) ----
        __syncthreads();
        if (tid == 0) {
            __threadfence();                       // release: h/c writes visible
            __atomic_fetch_add(bar, 1u, __ATOMIC_RELAXED);
            unsigned target = 32u * (unsigned)(t + 1);
            while (__atomic_fetch_add(bar, 0u, __ATOMIC_RELAXED) < target)
                __builtin_amdgcn_s_sleep(2);
            __threadfence();                       // acquire: see others' h writes
        }
        __syncthreads();
    }
}

// ---------------- host orchestration ----------------
extern "C" void kernel_launch(void* const* d_in, const int* in_sizes, int n_in,
                              void* d_out, int out_size, void* d_ws, size_t ws_size,
                              hipStream_t stream) {
    constexpr int B = 32, S = 512, F = 64, I = 512, H = 512, G = 2048;

    const float* x    = (const float*)d_in[0];
    const float* fut  = (const float*)d_in[1];
    const float* eh   = (const float*)d_in[2];
    const float* ec   = (const float*)d_in[3];
    const float* fc_w = (const float*)d_in[4];
    const float* fc_b = (const float*)d_in[5];
    const float* ewih = (const float*)d_in[6];
    const float* ewhh = (const float*)d_in[7];
    const float* ebih = (const float*)d_in[8];
    const float* ebhh = (const float*)d_in[9];
    const float* dwih = (const float*)d_in[10];
    const float* dwhh = (const float*)d_in[11];
    const float* dbih = (const float*)d_in[12];
    const float* dbhh = (const float*)d_in[13];
    float* out = (float*)d_out;

    char* ws = (char*)d_ws;
    size_t off = 0;
    auto alloc = [&](size_t bytes) -> char* {
        char* p = ws + off;
        off += (bytes + 255) & ~(size_t)255;
        return p;
    };

    bf16* x_bf    = (bf16*)alloc((size_t)B * S * I * 2);
    bf16* fut_bf  = (bf16*)alloc((size_t)B * F * I * 2);
    bf16* fcw_bf  = (bf16*)alloc((size_t)H * I * 2);
    bf16* ewih_bf = (bf16*)alloc((size_t)2 * G * H * 2);
    bf16* ewhh_bf = (bf16*)alloc((size_t)2 * G * H * 2);
    bf16* dwih_bf = (bf16*)alloc((size_t)2 * G * H * 2);
    bf16* dwhh_bf = (bf16*)alloc((size_t)2 * G * H * 2);
    bf16* xt_bf   = (bf16*)alloc((size_t)B * S * H * 2);
    bf16* h0seq   = (bf16*)alloc((size_t)B * S * H * 2);
    bf16* hD0seq  = (bf16*)alloc((size_t)B * F * H * 2);
    bf16* hbf     = (bf16*)alloc((size_t)2 * 2 * B * H * 2);  // [L][slot][B*H]
    float* hf     = (float*)alloc((size_t)2 * B * H * 4);
    float* cf     = (float*)alloc((size_t)2 * B * H * 4);
    unsigned* bar = (unsigned*)alloc(4 * 64 * sizeof(unsigned)); // 4 counters, 256B apart

    size_t xp32_bytes = (size_t)B * S * G * 4;
    bool xp32 = (ws_size - off) >= xp32_bytes + 4096;
    float* Xf = nullptr; bf16* Xb = nullptr;
    if (xp32) Xf = (float*)alloc(xp32_bytes);
    else      Xb = (bf16*)alloc((size_t)B * S * G * 2);

    auto cvt = [&](const float* s, bf16* d, int n) {
        int blocks = (n / 4 + 255) / 256;
        if (blocks > 4096) blocks = 4096;
        f2b_kernel<<<blocks, 256, 0, stream>>>(s, d, n);
    };
    cvt(x, x_bf, B * S * I);
    cvt(fut, fut_bf, B * F * I);
    cvt(fc_w, fcw_bf, H * I);
    cvt(ewih, ewih_bf, 2 * G * H);
    cvt(ewhh, ewhh_bf, 2 * G * H);
    cvt(dwih, dwih_bf, 2 * G * H);
    cvt(dwhh, dwhh_bf, 2 * G * H);

    init_state_kernel<<<128, 256, 0, stream>>>(eh, ec, hf, cf, hbf, bar);

    auto gemm = [&](const bf16* A, const bf16* W, const float* bias,
                    float* Cf_, bf16* Cb_, int M, int N, int K) {
        gemm_bt<<<dim3(N / 64, M / 64), 256, 0, stream>>>(A, W, bias, Cf_, Cb_, M, N, K);
    };

    // FC: xt = bf16(x @ fc_w^T + fc_b)
    gemm(x_bf, fcw_bf, fc_b, nullptr, xt_bf, B * S, H, I);

    auto run_phase = [&](const bf16* Whh_l, const float* bih_l, const float* bhh_l,
                         int layer, int T, int phase,
                         bf16* seq_base, long seq_stride,
                         float* out_base, long out_stride) {
        lstm_layer_persist<<<32, 256, 0, stream>>>(
            T,
            hbf + (size_t)(layer * 2 + 0) * (B * H),
            hbf + (size_t)(layer * 2 + 1) * (B * H),
            hf + (size_t)layer * B * H, cf + (size_t)layer * B * H,
            Whh_l, Xf, Xb, bih_l, bhh_l,
            seq_base, seq_stride, out_base, out_stride,
            bar + phase * 64);
    };

    // ---- Encoder layer 0 ----
    gemm(xt_bf, ewih_bf, nullptr, Xf, Xb, B * S, G, H);
    run_phase(ewhh_bf, ebih, ebhh, 0, S, 0, h0seq, (long)S * H, nullptr, 0);

    // ---- Encoder layer 1 ---- (sequence discarded; only final state matters)
    gemm(h0seq, ewih_bf + (size_t)G * H, nullptr, Xf, Xb, B * S, G, H);
    run_phase(ewhh_bf + (size_t)G * H, ebih + G, ebhh + G, 1, S, 1, nullptr, 0, nullptr, 0);

    // ---- Decoder layer 0 ---- (initial state = encoder finals: parity works out,
    // S even -> final h landed back in slot 0, which t=0 reads)
    gemm(fut_bf, dwih_bf, nullptr, Xf, Xb, B * F, G, H);
    run_phase(dwhh_bf, dbih, dbhh, 0, F, 2, hD0seq, (long)F * H, nullptr, 0);

    // ---- Decoder layer 1 ---- writes dec_out directly
    gemm(hD0seq, dwih_bf + (size_t)G * H, nullptr, Xf, Xb, B * F, G, H);
    run_phase(dwhh_bf + (size_t)G * H, dbih + G, dbhh + G, 1, F, 3, nullptr, 0, out, (long)F * H);

    // ---- Final decoder states ----
    tail_kernel<<<128, 256, 0, stream>>>(hf, cf, out);
}

// Round 3
// 12495.238 us; speedup vs baseline: 1.0584x; 1.0584x over previous
//
#include <hip/hip_runtime.h>
#include <hip/hip_bf16.h>

using bf16 = __hip_bfloat16;
typedef short v8s __attribute__((ext_vector_type(8)));   // 8 bf16 = 4 VGPRs
typedef float v4f __attribute__((ext_vector_type(4)));   // MFMA C/D frag

__device__ __forceinline__ float sigmoidf_(float x) {
    return 1.0f / (1.0f + __expf(-x));
}
__device__ __forceinline__ float tanhf_(float x) {
    return 1.0f - 2.0f / (__expf(2.0f * x) + 1.0f);
}
__device__ __forceinline__ unsigned short bfbits(float f) {
    bf16 h = __float2bfloat16(f);
    return *reinterpret_cast<unsigned short*>(&h);
}
__device__ __forceinline__ float bf2f(unsigned short u) {
    bf16 h = *reinterpret_cast<bf16*>(&u);
    return __bfloat162float(h);
}

// ---------------- fp32 -> bf16 converter ----------------
__global__ void f2b_kernel(const float* __restrict__ s, bf16* __restrict__ d, int n) {
    int idx = blockIdx.x * blockDim.x + threadIdx.x;
    int stride = gridDim.x * blockDim.x;
    for (int i = idx * 4; i < n; i += stride * 4) {
        float4 v = *reinterpret_cast<const float4*>(s + i);
        ushort4 u;
        u.x = bfbits(v.x); u.y = bfbits(v.y); u.z = bfbits(v.z); u.w = bfbits(v.w);
        *reinterpret_cast<ushort4*>(d + i) = u;
    }
}

// ---------------- init states + barrier counters ----------------
__global__ void init_state_kernel(const float* __restrict__ eh, const float* __restrict__ ec,
                                  float* __restrict__ hf, float* __restrict__ cf,
                                  bf16* __restrict__ hbf, unsigned* __restrict__ counters) {
    int idx = blockIdx.x * blockDim.x + threadIdx.x;
    if (idx < 4) counters[idx * 64] = 0u;   // 4 phase counters, 256B apart
    if (idx >= 2 * 32 * 512) return;
    int l = idx >> 14;          // / 16384
    int rem = idx & 16383;
    hf[idx] = eh[idx];
    cf[idx] = ec[idx];
    hbf[(l * 2 + 0) * 16384 + rem] = __float2bfloat16(eh[idx]);
}

// ---------------- tail: final states -> d_out ----------------
__global__ void tail_kernel(const float* __restrict__ hf, const float* __restrict__ cf,
                            float* __restrict__ out) {
    int idx = blockIdx.x * blockDim.x + threadIdx.x;
    if (idx >= 2 * 32 * 512) return;
    out[1048576 + idx] = hf[idx];
    out[1048576 + 32768 + idx] = cf[idx];
}

// ---------------- bf16 MFMA GEMM: C[M,N] = A[M,K] @ W[N,K]^T (+bias) ----------------
__global__ __launch_bounds__(256) void gemm_bt(
    const bf16* __restrict__ A, const bf16* __restrict__ W,
    const float* __restrict__ bias,
    float* __restrict__ Cf, bf16* __restrict__ Cb,
    int M, int N, int K) {
    __shared__ __align__(16) bf16 As[64][72];
    __shared__ __align__(16) bf16 Bs[64][72];
    const int tid = threadIdx.x;
    const int wave = tid >> 6, lane = tid & 63;
    const int lr = lane & 15, lq = lane >> 4;
    const int m0 = blockIdx.y * 64, n0 = blockIdx.x * 64;

    v4f acc[4];
#pragma unroll
    for (int n = 0; n < 4; ++n) acc[n] = (v4f){0.f, 0.f, 0.f, 0.f};

    for (int k0 = 0; k0 < K; k0 += 64) {
        __syncthreads();
#pragma unroll
        for (int c = tid; c < 512; c += 256) {
            int row = c >> 3, c8 = (c & 7) * 8;
            *reinterpret_cast<v8s*>(&As[row][c8]) =
                *reinterpret_cast<const v8s*>(A + (size_t)(m0 + row) * K + k0 + c8);
            *reinterpret_cast<v8s*>(&Bs[row][c8]) =
                *reinterpret_cast<const v8s*>(W + (size_t)(n0 + row) * K + k0 + c8);
        }
        __syncthreads();
#pragma unroll
        for (int kk = 0; kk < 2; ++kk) {
            v8s a = *reinterpret_cast<const v8s*>(&As[wave * 16 + lr][kk * 32 + lq * 8]);
#pragma unroll
            for (int n = 0; n < 4; ++n) {
                v8s b = *reinterpret_cast<const v8s*>(&Bs[n * 16 + lr][kk * 32 + lq * 8]);
                acc[n] = __builtin_amdgcn_mfma_f32_16x16x32_bf16(a, b, acc[n], 0, 0, 0);
            }
        }
    }
#pragma unroll
    for (int n = 0; n < 4; ++n) {
        int col = n0 + n * 16 + lr;
        float bv = bias ? bias[col] : 0.0f;
#pragma unroll
        for (int r = 0; r < 4; ++r) {
            int row = m0 + wave * 16 + lq * 4 + r;
            float v = acc[n][r] + bv;
            if (Cf) Cf[(size_t)row * N + col] = v;
            if (Cb) Cb[(size_t)row * N + col] = __float2bfloat16(v);
        }
    }
}

// ---------------- persistent LSTM layer (fence-free coherent h exchange) ----------------
// 32 WGs x 256 thr, co-resident. WG j owns hidden cols [j*16, j*16+16).
// Wave w = gate w (i,f,g,o). Whh slice pinned in VGPRs. c register-resident.
// h ping-pong: instruction-level device-coherent (relaxed agent atomics) — NO cache fences.
__global__ __launch_bounds__(256) void lstm_layer_persist(
    int T,
    bf16* __restrict__ h0, bf16* __restrict__ h1,   // ping-pong [32*512] bf16
    float* __restrict__ hf, float* __restrict__ cf,  // [32*512] fp32 state
    const bf16* __restrict__ Whh,                    // [2048][512]
    const float* __restrict__ xpf,                   // fp32 xproj [(b*T+t)*2048] or null
    const bf16* __restrict__ xpb,                    // bf16 xproj or null
    const float* __restrict__ bih, const float* __restrict__ bhh,
    bf16* __restrict__ seq, long seq_stride_b,       // optional bf16 h seq out
    float* __restrict__ outf, long out_stride_b,     // optional fp32 h seq out
    unsigned* __restrict__ bar)
{
    __shared__ float gs[4][32][16];
    __shared__ float bias_s[4][16];
    const int tid = threadIdx.x;
    const int wave = tid >> 6, lane = tid & 63;
    const int lr = lane & 15, lq = lane >> 4;
    const int hc0 = blockIdx.x * 16;

    if (tid < 64) {
        int g = tid >> 4, col = tid & 15;
        bias_s[g][col] = bih[g * 512 + hc0 + col] + bhh[g * 512 + hc0 + col];
    }

    // pointwise ownership: batch pb, cols pc & pc+1 (one iteration, c in regs)
    const int pb = tid >> 3;
    const int pc = (tid & 7) * 2;
    const int pgc = hc0 + pc;

    float c0, c1;
    {
        size_t sidx = (size_t)pb * 512 + pgc;
        c0 = cf[sidx]; c1 = cf[sidx + 1];
    }

    // Whh slice (gate `wave`, cols hc0+lr) pinned into 64 VGPRs.
    v8s breg[16];
    {
        const bf16* wrow = Whh + (size_t)(wave * 512 + hc0 + lr) * 512 + lq * 8;
#pragma unroll
        for (int kk = 0; kk < 16; ++kk)
            breg[kk] = *reinterpret_cast<const v8s*>(wrow + kk * 32);
    }
    asm volatile("" : "+v"(breg[0]), "+v"(breg[1]), "+v"(breg[2]), "+v"(breg[3]),
                      "+v"(breg[4]), "+v"(breg[5]), "+v"(breg[6]), "+v"(breg[7]),
                      "+v"(breg[8]), "+v"(breg[9]), "+v"(breg[10]), "+v"(breg[11]),
                      "+v"(breg[12]), "+v"(breg[13]), "+v"(breg[14]), "+v"(breg[15]));
    __syncthreads();

    for (int t = 0; t < T; ++t) {
        const bf16* hin = (t & 1) ? h1 : h0;
        bf16* hout      = (t & 1) ? h0 : h1;

        // ---- prefetch xp for this step (independent of h, hides HBM latency) ----
        float xi0, xi1, xf0, xf1, xg0, xg1, xo0, xo1;
        if (xpf) {
            const float* xp = xpf + ((size_t)pb * T + t) * 2048;
            float2 a = *reinterpret_cast<const float2*>(xp + pgc);
            float2 b = *reinterpret_cast<const float2*>(xp + 512 + pgc);
            float2 c = *reinterpret_cast<const float2*>(xp + 1024 + pgc);
            float2 d = *reinterpret_cast<const float2*>(xp + 1536 + pgc);
            xi0 = a.x; xi1 = a.y; xf0 = b.x; xf1 = b.y;
            xg0 = c.x; xg1 = c.y; xo0 = d.x; xo1 = d.y;
        } else {
            const bf16* xp = xpb + ((size_t)pb * T + t) * 2048;
            unsigned a = *reinterpret_cast<const unsigned*>(xp + pgc);
            unsigned b = *reinterpret_cast<const unsigned*>(xp + 512 + pgc);
            unsigned c = *reinterpret_cast<const unsigned*>(xp + 1024 + pgc);
            unsigned d = *reinterpret_cast<const unsigned*>(xp + 1536 + pgc);
            xi0 = bf2f(a & 0xffff); xi1 = bf2f(a >> 16);
            xf0 = bf2f(b & 0xffff); xf1 = bf2f(b >> 16);
            xg0 = bf2f(c & 0xffff); xg1 = bf2f(c >> 16);
            xo0 = bf2f(d & 0xffff); xo1 = bf2f(d >> 16);
        }

        // ---- hidden GEMM: A loads are device-coherent 8B relaxed atomics ----
        unsigned long long* hbase = (unsigned long long*)hin;
        v4f acc0 = (v4f){0.f, 0.f, 0.f, 0.f};
        v4f acc1 = (v4f){0.f, 0.f, 0.f, 0.f};
#pragma unroll 4
        for (int kk = 0; kk < 16; ++kk) {
            union { unsigned long long u[2]; v8s v; } a0u, a1u;
            unsigned long long* p0 = hbase + (size_t)lr * 128 + lq * 2 + kk * 8;
            a0u.u[0] = __hip_atomic_load(p0,     __ATOMIC_RELAXED, __HIP_MEMORY_SCOPE_AGENT);
            a0u.u[1] = __hip_atomic_load(p0 + 1, __ATOMIC_RELAXED, __HIP_MEMORY_SCOPE_AGENT);
            unsigned long long* p1 = p0 + 2048;  // batches 16..31
            a1u.u[0] = __hip_atomic_load(p1,     __ATOMIC_RELAXED, __HIP_MEMORY_SCOPE_AGENT);
            a1u.u[1] = __hip_atomic_load(p1 + 1, __ATOMIC_RELAXED, __HIP_MEMORY_SCOPE_AGENT);
            acc0 = __builtin_amdgcn_mfma_f32_16x16x32_bf16(a0u.v, breg[kk], acc0, 0, 0, 0);
            acc1 = __builtin_amdgcn_mfma_f32_16x16x32_bf16(a1u.v, breg[kk], acc1, 0, 0, 0);
        }
#pragma unroll
        for (int r = 0; r < 4; ++r) {
            gs[wave][lq * 4 + r][lr]      = acc0[r];
            gs[wave][16 + lq * 4 + r][lr] = acc1[r];
        }
        __syncthreads();

        // ---- pointwise: this thread's (pb, pc..pc+1) ----
        float gi0 = gs[0][pb][pc]     + xi0 + bias_s[0][pc];
        float gi1 = gs[0][pb][pc + 1] + xi1 + bias_s[0][pc + 1];
        float gf0 = gs[1][pb][pc]     + xf0 + bias_s[1][pc];
        float gf1 = gs[1][pb][pc + 1] + xf1 + bias_s[1][pc + 1];
        float gg0 = gs[2][pb][pc]     + xg0 + bias_s[2][pc];
        float gg1 = gs[2][pb][pc + 1] + xg1 + bias_s[2][pc + 1];
        float go0 = gs[3][pb][pc]     + xo0 + bias_s[3][pc];
        float go1 = gs[3][pb][pc + 1] + xo1 + bias_s[3][pc + 1];

        c0 = sigmoidf_(gf0) * c0 + sigmoidf_(gi0) * tanhf_(gg0);
        c1 = sigmoidf_(gf1) * c1 + sigmoidf_(gi1) * tanhf_(gg1);
        float h0v = sigmoidf_(go0) * tanhf_(c0);
        float h1v = sigmoidf_(go1) * tanhf_(c1);

        unsigned hp = (unsigned)bfbits(h0v) | ((unsigned)bfbits(h1v) << 16);
        // device-coherent write-through (visible at MALL, no fence needed)
        __hip_atomic_store(reinterpret_cast<unsigned*>(hout + (size_t)pb * 512 + pgc),
                           hp, __ATOMIC_RELAXED, __HIP_MEMORY_SCOPE_AGENT);
        if (seq)
            *reinterpret_cast<unsigned*>(seq + (size_t)pb * seq_stride_b + (size_t)t * 512 + pgc) = hp;
        if (outf) {
            float2 hv; hv.x = h0v; hv.y = h1v;
            *reinterpret_cast<float2*>(outf + (size_t)pb * out_stride_b + (size_t)t * 512 + pgc) = hv;
        }
        if (t == T - 1) {
            size_t sidx = (size_t)pb * 512 + pgc;
            hf[sidx] = h0v; hf[sidx + 1] = h1v;
            cf[sidx] = c0;  cf[sidx + 1] = c1;
        }

        // ---- fence-free grid barrier ----
        // __syncthreads drains vmcnt(0) per wave -> all sc-coherent h stores are
        // at the MALL before any thread arrives; then one relaxed agent add.
        __syncthreads();
        if (tid == 0) {
            __hip_atomic_fetch_add(bar, 1u, __ATOMIC_RELAXED, __HIP_MEMORY_SCOPE_AGENT);
            unsigned target = 32u * (unsigned)(t + 1);
            while (__hip_atomic_load(bar, __ATOMIC_RELAXED, __HIP_MEMORY_SCOPE_AGENT) < target)
                __builtin_amdgcn_s_sleep(1);
        }
        __syncthreads();
    }
}

// ---------------- host orchestration ----------------
extern "C" void kernel_launch(void* const* d_in, const int* in_sizes, int n_in,
                              void* d_out, int out_size, void* d_ws, size_t ws_size,
                              hipStream_t stream) {
    constexpr int B = 32, S = 512, F = 64, I = 512, H = 512, G = 2048;

    const float* x    = (const float*)d_in[0];
    const float* fut  = (const float*)d_in[1];
    const float* eh   = (const float*)d_in[2];
    const float* ec   = (const float*)d_in[3];
    const float* fc_w = (const float*)d_in[4];
    const float* fc_b = (const float*)d_in[5];
    const float* ewih = (const float*)d_in[6];
    const float* ewhh = (const float*)d_in[7];
    const float* ebih = (const float*)d_in[8];
    const float* ebhh = (const float*)d_in[9];
    const float* dwih = (const float*)d_in[10];
    const float* dwhh = (const float*)d_in[11];
    const float* dbih = (const float*)d_in[12];
    const float* dbhh = (const float*)d_in[13];
    float* out = (float*)d_out;

    char* ws = (char*)d_ws;
    size_t off = 0;
    auto alloc = [&](size_t bytes) -> char* {
        char* p = ws + off;
        off += (bytes + 255) & ~(size_t)255;
        return p;
    };

    bf16* x_bf    = (bf16*)alloc((size_t)B * S * I * 2);
    bf16* fut_bf  = (bf16*)alloc((size_t)B * F * I * 2);
    bf16* fcw_bf  = (bf16*)alloc((size_t)H * I * 2);
    bf16* ewih_bf = (bf16*)alloc((size_t)2 * G * H * 2);
    bf16* ewhh_bf = (bf16*)alloc((size_t)2 * G * H * 2);
    bf16* dwih_bf = (bf16*)alloc((size_t)2 * G * H * 2);
    bf16* dwhh_bf = (bf16*)alloc((size_t)2 * G * H * 2);
    bf16* xt_bf   = (bf16*)alloc((size_t)B * S * H * 2);
    bf16* h0seq   = (bf16*)alloc((size_t)B * S * H * 2);
    bf16* hD0seq  = (bf16*)alloc((size_t)B * F * H * 2);
    bf16* hbf     = (bf16*)alloc((size_t)2 * 2 * B * H * 2);  // [L][slot][B*H]
    float* hf     = (float*)alloc((size_t)2 * B * H * 4);
    float* cf     = (float*)alloc((size_t)2 * B * H * 4);
    unsigned* bar = (unsigned*)alloc(4 * 64 * sizeof(unsigned)); // 4 counters, 256B apart

    size_t xp32_bytes = (size_t)B * S * G * 4;
    bool xp32 = (ws_size - off) >= xp32_bytes + 4096;
    float* Xf = nullptr; bf16* Xb = nullptr;
    if (xp32) Xf = (float*)alloc(xp32_bytes);
    else      Xb = (bf16*)alloc((size_t)B * S * G * 2);

    auto cvt = [&](const float* s, bf16* d, int n) {
        int blocks = (n / 4 + 255) / 256;
        if (blocks > 4096) blocks = 4096;
        f2b_kernel<<<blocks, 256, 0, stream>>>(s, d, n);
    };
    cvt(x, x_bf, B * S * I);
    cvt(fut, fut_bf, B * F * I);
    cvt(fc_w, fcw_bf, H * I);
    cvt(ewih, ewih_bf, 2 * G * H);
    cvt(ewhh, ewhh_bf, 2 * G * H);
    cvt(dwih, dwih_bf, 2 * G * H);
    cvt(dwhh, dwhh_bf, 2 * G * H);

    init_state_kernel<<<128, 256, 0, stream>>>(eh, ec, hf, cf, hbf, bar);

    auto gemm = [&](const bf16* A, const bf16* W, const float* bias,
                    float* Cf_, bf16* Cb_, int M, int N, int K) {
        gemm_bt<<<dim3(N / 64, M / 64), 256, 0, stream>>>(A, W, bias, Cf_, Cb_, M, N, K);
    };

    // FC: xt = bf16(x @ fc_w^T + fc_b)
    gemm(x_bf, fcw_bf, fc_b, nullptr, xt_bf, B * S, H, I);

    auto run_phase = [&](const bf16* Whh_l, const float* bih_l, const float* bhh_l,
                         int layer, int T, int phase,
                         bf16* seq_base, long seq_stride,
                         float* out_base, long out_stride) {
        lstm_layer_persist<<<32, 256, 0, stream>>>(
            T,
            hbf + (size_t)(layer * 2 + 0) * (B * H),
            hbf + (size_t)(layer * 2 + 1) * (B * H),
            hf + (size_t)layer * B * H, cf + (size_t)layer * B * H,
            Whh_l, Xf, Xb, bih_l, bhh_l,
            seq_base, seq_stride, out_base, out_stride,
            bar + phase * 64);
    };

    // ---- Encoder layer 0 ----
    gemm(xt_bf, ewih_bf, nullptr, Xf, Xb, B * S, G, H);
    run_phase(ewhh_bf, ebih, ebhh, 0, S, 0, h0seq, (long)S * H, nullptr, 0);

    // ---- Encoder layer 1 ---- (sequence discarded; only final state matters)
    gemm(h0seq, ewih_bf + (size_t)G * H, nullptr, Xf, Xb, B * S, G, H);
    run_phase(ewhh_bf + (size_t)G * H, ebih + G, ebhh + G, 1, S, 1, nullptr, 0, nullptr, 0);

    // ---- Decoder layer 0 ---- (initial state = encoder finals; S even -> h in slot 0)
    gemm(fut_bf, dwih_bf, nullptr, Xf, Xb, B * F, G, H);
    run_phase(dwhh_bf, dbih, dbhh, 0, F, 2, hD0seq, (long)F * H, nullptr, 0);

    // ---- Decoder layer 1 ---- writes dec_out directly
    gemm(hD0seq, dwih_bf + (size_t)G * H, nullptr, Xf, Xb, B * F, G, H);
    run_phase(dwhh_bf + (size_t)G * H, dbih + G, dbhh + G, 1, F, 3, nullptr, 0, out, (long)F * H);

    // ---- Final decoder states ----
    tail_kernel<<<128, 256, 0, stream>>>(hf, cf, out);
}